// Round 7
// baseline (1908.866 us; speedup 1.0000x reference)
//
#include <hip/hip_runtime.h>

#define DIM 128
#define BN 128              // nodes per bucket (dl fits in 7 bits; src in 17)
#define SCAN_CHUNK 512

typedef __attribute__((ext_vector_type(8))) short bf16x8;
typedef __attribute__((ext_vector_type(4))) float f32x4;

__device__ inline short f2bf(float f) {
    unsigned u = __builtin_bit_cast(unsigned, f);
    return (short)((u + 0x8000u) >> 16);
}

// ===========================================================================
// NEW PATH: bucketed aggregation (no CSR fill, no per-node gather).
// ===========================================================================

// Per-bucket record histogram: 2 records per edge (one per direction).
__global__ __launch_bounds__(256) void hist_kernel(
    const int* __restrict__ ei, int* __restrict__ hist, int E, int nb)
{
    __shared__ int h[1024];
    for (int i = threadIdx.x; i < nb; i += 256) h[i] = 0;
    __syncthreads();
    const int stride = gridDim.x * 256;
    for (int e = blockIdx.x * 256 + threadIdx.x; e < E; e += stride) {
        int s = ei[e], d = ei[E + e];
        atomicAdd(&h[d >> 7], 1);
        atomicAdd(&h[s >> 7], 1);
    }
    __syncthreads();
    for (int i = threadIdx.x; i < nb; i += 256)
        if (h[i]) atomicAdd(&hist[i], h[i]);
}

// Single-block scan over <=1024 bucket counts -> base & cursor.
__global__ __launch_bounds__(1024) void bscan_kernel(
    const int* __restrict__ hist, int* __restrict__ base,
    int* __restrict__ cursor, int nb)
{
    __shared__ int s[1024];
    const int t = threadIdx.x;
    int v = (t < nb) ? hist[t] : 0;
    s[t] = v;
    __syncthreads();
    for (int off = 1; off < 1024; off <<= 1) {
        int u = (t >= off) ? s[t - off] : 0;
        __syncthreads();
        s[t] += u;
        __syncthreads();
    }
    if (t < nb) { base[t] = s[t] - v; cursor[t] = s[t] - v; }
}

// Emit packed records into bucket regions. Record = (dst&127)<<17 | src.
__global__ __launch_bounds__(256) void bin_kernel(
    const int* __restrict__ ei, int* __restrict__ cursor,
    unsigned* __restrict__ recs, int E)
{
    const int stride = gridDim.x * 256;
    for (int e = blockIdx.x * 256 + threadIdx.x; e < E; e += stride) {
        int s = ei[e], d = ei[E + e];
        int p0 = atomicAdd(&cursor[d >> 7], 1);
        recs[p0] = ((unsigned)(d & 127) << 17) | (unsigned)s;
        int p1 = atomicAdd(&cursor[s >> 7], 1);
        recs[p1] = ((unsigned)(s & 127) << 17) | (unsigned)d;
    }
}

// One block per bucket: accumulate x[src] rows into LDS tile via ds-atomics,
// count degrees in LDS, write normalized rows once (coalesced).
// LDS 64KB tile -> 2 blocks/CU. Bank pattern lane%32 -> 2-way (free).
__global__ __launch_bounds__(256) void aggregate_kernel(
    const float* __restrict__ x,
    const int* __restrict__ base, const int* __restrict__ hist,
    const unsigned* __restrict__ recs,
    float* __restrict__ agg,            // = d_out
    int N)
{
    __shared__ float sagg[BN * DIM];
    __shared__ int ldeg[BN];

    const int b = blockIdx.x;
    const int t = threadIdx.x;

    for (int i = t; i < BN * (DIM / 4); i += 256)
        ((float4*)sagg)[i] = make_float4(0.f, 0.f, 0.f, 0.f);
    if (t < BN) ldeg[t] = 0;
    __syncthreads();

    const int start = base[b];
    const int cnt = hist[b];
    const int wave = t >> 6, lane = t & 63;

    for (int j0 = wave * 64; j0 < cnt; j0 += 256) {
        const int m = min(64, cnt - j0);
        unsigned rec = 0;
        if (lane < m) rec = recs[start + j0 + lane];
        int jj = 0;
        for (; jj + 4 <= m; jj += 4) {
            unsigned r0 = __shfl(rec, jj);
            unsigned r1 = __shfl(rec, jj + 1);
            unsigned r2 = __shfl(rec, jj + 2);
            unsigned r3 = __shfl(rec, jj + 3);
            int s0 = r0 & 0x1FFFF, d0 = r0 >> 17;
            int s1 = r1 & 0x1FFFF, d1 = r1 >> 17;
            int s2 = r2 & 0x1FFFF, d2 = r2 >> 17;
            int s3 = r3 & 0x1FFFF, d3 = r3 >> 17;
            float a0 = x[(size_t)s0 * DIM + lane];
            float b0 = x[(size_t)s0 * DIM + 64 + lane];
            float a1 = x[(size_t)s1 * DIM + lane];
            float b1 = x[(size_t)s1 * DIM + 64 + lane];
            float a2 = x[(size_t)s2 * DIM + lane];
            float b2 = x[(size_t)s2 * DIM + 64 + lane];
            float a3 = x[(size_t)s3 * DIM + lane];
            float b3 = x[(size_t)s3 * DIM + 64 + lane];
            atomicAdd(&sagg[d0 * DIM + lane], a0);
            atomicAdd(&sagg[d0 * DIM + 64 + lane], b0);
            atomicAdd(&sagg[d1 * DIM + lane], a1);
            atomicAdd(&sagg[d1 * DIM + 64 + lane], b1);
            atomicAdd(&sagg[d2 * DIM + lane], a2);
            atomicAdd(&sagg[d2 * DIM + 64 + lane], b2);
            atomicAdd(&sagg[d3 * DIM + lane], a3);
            atomicAdd(&sagg[d3 * DIM + 64 + lane], b3);
            if (lane == 0) {
                atomicAdd(&ldeg[d0], 1); atomicAdd(&ldeg[d1], 1);
                atomicAdd(&ldeg[d2], 1); atomicAdd(&ldeg[d3], 1);
            }
        }
        for (; jj < m; ++jj) {
            unsigned r = __shfl(rec, jj);
            int src = r & 0x1FFFF, dl = r >> 17;
            float v0 = x[(size_t)src * DIM + lane];
            float v1 = x[(size_t)src * DIM + 64 + lane];
            atomicAdd(&sagg[dl * DIM + lane], v0);
            atomicAdd(&sagg[dl * DIM + 64 + lane], v1);
            if (lane == 0) atomicAdd(&ldeg[dl], 1);
        }
    }
    __syncthreads();

    const int node0 = b << 7;
    for (int i = t; i < BN * (DIM / 4); i += 256) {
        int row = i >> 5, c4 = i & 31;
        int node = node0 + row;
        if (node < N) {
            float inv = 1.0f / fmaxf((float)ldeg[row], 1.0f);
            float4 v = ((float4*)sagg)[i];
            v.x *= inv; v.y *= inv; v.z *= inv; v.w *= inv;
            ((float4*)agg)[(size_t)node * 32 + c4] = v;
        }
    }
}

// ===========================================================================
// W pre-convert + MFMA GEMM (round-5/6 proven, unchanged).
// ===========================================================================
__global__ __launch_bounds__(256) void wconv_kernel(
    const float* __restrict__ Ws, const float* __restrict__ Wn,
    unsigned short* __restrict__ Wb)
{
    int i = blockIdx.x * 256 + threadIdx.x;
    int n = i >> 8, k = i & 255;
    float v = (k < DIM) ? Ws[n * DIM + k] : Wn[n * DIM + (k - DIM)];
    Wb[i] = (unsigned short)f2bf(v);
}

__global__ __launch_bounds__(256) void mfma_gemm_kernel(
    const float* __restrict__ x,
    const float* __restrict__ agg,            // = d_out
    const unsigned short* __restrict__ Wb,    // [128][256] bf16
    const float* __restrict__ bias,
    float* __restrict__ out,
    int M)
{
    const int wave = threadIdx.x >> 6;
    const int lane = threadIdx.x & 63;
    const int row0 = blockIdx.x * 64 + wave * 16;
    if (row0 >= M) return;
    const int m = lane & 15;
    const int quad = lane >> 4;

    f32x4 acc[8];
    #pragma unroll
    for (int nt = 0; nt < 8; ++nt) acc[nt] = (f32x4){0.f, 0.f, 0.f, 0.f};

    const float* arow_x = x   + (size_t)(row0 + m) * DIM + quad * 8;
    const float* arow_g = agg + (size_t)(row0 + m) * DIM + quad * 8;
    const unsigned short* brow = Wb + (size_t)m * 256 + quad * 8;

    #pragma unroll
    for (int ks = 0; ks < 8; ++ks) {
        const float* ap = (ks < 4) ? (arow_x + ks * 32) : (arow_g + (ks - 4) * 32);
        float4 lo = *(const float4*)(ap);
        float4 hi = *(const float4*)(ap + 4);
        bf16x8 af;
        af[0] = f2bf(lo.x); af[1] = f2bf(lo.y); af[2] = f2bf(lo.z); af[3] = f2bf(lo.w);
        af[4] = f2bf(hi.x); af[5] = f2bf(hi.y); af[6] = f2bf(hi.z); af[7] = f2bf(hi.w);
        #pragma unroll
        for (int nt = 0; nt < 8; ++nt) {
            bf16x8 bf = *(const bf16x8*)(brow + (size_t)nt * 16 * 256 + ks * 32);
            acc[nt] = __builtin_amdgcn_mfma_f32_16x16x32_bf16(af, bf, acc[nt], 0, 0, 0);
        }
    }

    #pragma unroll
    for (int nt = 0; nt < 8; ++nt) {
        int c = nt * 16 + m;
        float b = bias[c];
        #pragma unroll
        for (int r = 0; r < 4; ++r) {
            int row = row0 + quad * 4 + r;
            out[(size_t)row * DIM + c] = fmaxf(acc[nt][r] + b, 0.0f);
        }
    }
}

// ===========================================================================
// FALLBACK PATH (round-6 CSR, used only if ws too small for buckets).
// ===========================================================================
__global__ __launch_bounds__(256) void count_kernel(
    const int* __restrict__ ei, int* __restrict__ deg, int E)
{
    int e = blockIdx.x * blockDim.x + threadIdx.x;
    if (e >= E) return;
    atomicAdd(deg + ei[e], 1);
    atomicAdd(deg + ei[E + e], 1);
}

__global__ __launch_bounds__(1024) void scan_kernel(
    const int* __restrict__ deg, int* __restrict__ rowptr,
    int* __restrict__ cursor, int N)
{
    __shared__ int sums[1024];
    const int t = threadIdx.x;
    const int chunk = (N + 1023) >> 10;
    const int lo = t * chunk;
    const int hi = min(lo + chunk, N);
    int s = 0;
    for (int i = lo; i < hi; ++i) s += deg[i];
    sums[t] = s;
    __syncthreads();
    for (int off = 1; off < 1024; off <<= 1) {
        int v = (t >= off) ? sums[t - off] : 0;
        __syncthreads();
        sums[t] += v;
        __syncthreads();
    }
    int run = (t == 0) ? 0 : sums[t - 1];
    for (int i = lo; i < hi; ++i) {
        rowptr[i] = run;
        cursor[i] = run;
        run += deg[i];
    }
    if (t == 1023) rowptr[N] = sums[1023];
}

__global__ __launch_bounds__(256) void fill_kernel(
    const int* __restrict__ ei, int* __restrict__ cursor,
    int* __restrict__ col, int E)
{
    int e = blockIdx.x * blockDim.x + threadIdx.x;
    if (e >= E) return;
    int s = ei[e];
    int d = ei[E + e];
    int p0 = atomicAdd(cursor + d, 1);  col[p0] = s;
    int p1 = atomicAdd(cursor + s, 1);  col[p1] = d;
}

__global__ __launch_bounds__(256) void gather_kernel(
    const float* __restrict__ x,
    const int* __restrict__ rowptr,
    const int* __restrict__ deg,
    const int* __restrict__ col,
    float* __restrict__ agg, int N)
{
    const int n = blockIdx.x * 4 + (threadIdx.x >> 6);
    if (n >= N) return;
    const int lane = threadIdx.x & 63;
    const int start = rowptr[n];
    const int cnt = deg[n];
    const float2* x2 = (const float2*)x;
    float2 acc = make_float2(0.0f, 0.0f);
    for (int j0 = 0; j0 < cnt; j0 += 64) {
        int idx = 0;
        if (j0 + lane < cnt) idx = col[start + j0 + lane];
        const int m = min(64, cnt - j0);
        for (int jj = 0; jj < m; ++jj) {
            int nb = __shfl(idx, jj);
            float2 v = x2[(size_t)nb * 64 + lane];
            acc.x += v.x; acc.y += v.y;
        }
    }
    const float inv = 1.0f / fmaxf((float)cnt, 1.0f);
    acc.x *= inv; acc.y *= inv;
    ((float2*)agg)[(size_t)n * 64 + lane] = acc;
}

extern "C" void kernel_launch(void* const* d_in, const int* in_sizes, int n_in,
                              void* d_out, int out_size, void* d_ws, size_t ws_size,
                              hipStream_t stream) {
    const float* x    = (const float*)d_in[0];
    const int* ei     = (const int*)d_in[1];   // int32 on device (harness converts)
    const float* Ws   = (const float*)d_in[3];
    const float* Wn   = (const float*)d_in[4];
    const float* bias = (const float*)d_in[5];
    float* out        = (float*)d_out;

    const int N = in_sizes[0] / DIM;      // 100000
    const int E = in_sizes[1] / 2;        // 800000
    float* agg = out;

    const int nb = (N + BN - 1) >> 7;     // buckets
    const size_t wb_bytes = (size_t)DIM * 256 * sizeof(unsigned short);  // 64 KB

    // New-path ws layout: hist[1024] | base[1024] | cursor[1024] | recs[2E] | Wb
    const size_t new_bytes = 3 * 1024 * sizeof(int) + (size_t)2 * E * sizeof(unsigned) + wb_bytes;

    if (nb <= 1024 && ws_size >= new_bytes) {
        int* hist   = (int*)d_ws;
        int* base   = hist + 1024;
        int* cursor = base + 1024;
        unsigned* recs = (unsigned*)(cursor + 1024);
        unsigned short* Wb = (unsigned short*)(recs + (size_t)2 * E);

        hipMemsetAsync(hist, 0, 1024 * sizeof(int), stream);
        hist_kernel<<<256, 256, 0, stream>>>(ei, hist, E, nb);
        bscan_kernel<<<1, 1024, 0, stream>>>(hist, base, cursor, nb);
        bin_kernel<<<256, 256, 0, stream>>>(ei, cursor, recs, E);
        aggregate_kernel<<<nb, 256, 0, stream>>>(x, base, hist, recs, agg, N);

        wconv_kernel<<<(DIM * 256) / 256, 256, 0, stream>>>(Ws, Wn, Wb);
        mfma_gemm_kernel<<<(N + 63) / 64, 256, 0, stream>>>(x, agg, Wb, bias, out, N);
    } else {
        // Fallback: round-6 CSR path.
        int* deg    = (int*)d_ws;
        int* rowptr = deg + N;
        int* cursor = rowptr + N + 1;
        int* col    = cursor + N;
        unsigned short* Wb = (unsigned short*)(col + (size_t)2 * E);

        hipMemsetAsync(deg, 0, (size_t)N * sizeof(int), stream);
        int eb = (E + 255) / 256;
        count_kernel<<<eb, 256, 0, stream>>>(ei, deg, E);
        scan_kernel<<<1, 1024, 0, stream>>>(deg, rowptr, cursor, N);
        fill_kernel<<<eb, 256, 0, stream>>>(ei, cursor, col, E);
        gather_kernel<<<(N + 3) / 4, 256, 0, stream>>>(x, rowptr, deg, col, agg, N);
        wconv_kernel<<<(DIM * 256) / 256, 256, 0, stream>>>(Ws, Wn, Wb);
        mfma_gemm_kernel<<<(N + 63) / 64, 256, 0, stream>>>(x, agg, Wb, bias, out, N);
    }
}

// Round 8
// 674.839 us; speedup vs baseline: 2.8286x; 2.8286x over previous
//
#include <hip/hip_runtime.h>

#define DIM 128
#define BN 128              // nodes per bucket; dst-local 7 bits, src 17 bits

typedef __attribute__((ext_vector_type(8))) short bf16x8;
typedef __attribute__((ext_vector_type(4))) float f32x4;

__device__ inline short f2bf(float f) {
    unsigned u = __builtin_bit_cast(unsigned, f);
    return (short)((u + 0x8000u) >> 16);
}

// ===========================================================================
// Bucketed CSR construction: hist -> bscan -> bin -> localsort.
// Write-amp fix: bin scatters to 782 sequential frontiers (50 KB of active
// lines, L2-resident) instead of fill's 100k frontiers (107 MB HBM writes).
// ===========================================================================

__global__ __launch_bounds__(256) void hist_kernel(
    const int* __restrict__ ei, int* __restrict__ hist, int E, int nb)
{
    __shared__ int h[1024];
    for (int i = threadIdx.x; i < nb; i += 256) h[i] = 0;
    __syncthreads();
    const int stride = gridDim.x * 256;
    for (int e = blockIdx.x * 256 + threadIdx.x; e < E; e += stride) {
        int s = ei[e], d = ei[E + e];
        atomicAdd(&h[d >> 7], 1);
        atomicAdd(&h[s >> 7], 1);
    }
    __syncthreads();
    for (int i = threadIdx.x; i < nb; i += 256)
        if (h[i]) atomicAdd(&hist[i], h[i]);
}

__global__ __launch_bounds__(1024) void bscan_kernel(
    const int* __restrict__ hist, int* __restrict__ base,
    int* __restrict__ cursor, int nb)
{
    __shared__ int s[1024];
    const int t = threadIdx.x;
    int v = (t < nb) ? hist[t] : 0;
    s[t] = v;
    __syncthreads();
    for (int off = 1; off < 1024; off <<= 1) {
        int u = (t >= off) ? s[t - off] : 0;
        __syncthreads();
        s[t] += u;
        __syncthreads();
    }
    if (t < nb) { base[t] = s[t] - v; cursor[t] = s[t] - v; }
}

// Record = (dst&127)<<17 | src  (src < 2^17, bucket-local dst < 128).
__global__ __launch_bounds__(256) void bin_kernel(
    const int* __restrict__ ei, int* __restrict__ cursor,
    unsigned* __restrict__ recs, int E)
{
    const int stride = gridDim.x * 256;
    for (int e = blockIdx.x * 256 + threadIdx.x; e < E; e += stride) {
        int s = ei[e], d = ei[E + e];
        int p0 = atomicAdd(&cursor[d >> 7], 1);
        recs[p0] = ((unsigned)(d & 127) << 17) | (unsigned)s;
        int p1 = atomicAdd(&cursor[s >> 7], 1);
        recs[p1] = ((unsigned)(s & 127) << 17) | (unsigned)d;
    }
}

// One block per bucket: node-level counting sort entirely in LDS; writes
// col into the bucket's contiguous region (full cache lines, no write amp)
// and emits global rowptr/deg per node (no node-level scan needed).
__global__ __launch_bounds__(256) void localsort_kernel(
    const unsigned* __restrict__ recs,
    const int* __restrict__ base, const int* __restrict__ hist,
    int* __restrict__ rowptr, int* __restrict__ deg,
    int* __restrict__ col, int N)
{
    __shared__ int lcnt[BN];
    __shared__ int lscan[BN];
    __shared__ int lcur[BN];

    const int b = blockIdx.x;
    const int t = threadIdx.x;
    const int start = base[b];
    const int cnt = hist[b];

    if (t < BN) lcnt[t] = 0;
    __syncthreads();

    // Pass 1: count records per local node.
    for (int j = t; j < cnt; j += 256)
        atomicAdd(&lcnt[recs[start + j] >> 17], 1);
    __syncthreads();

    // Exclusive scan of 128 counts (Hillis-Steele; all threads hit syncs).
    if (t < BN) lscan[t] = lcnt[t];
    __syncthreads();
    for (int off = 1; off < BN; off <<= 1) {
        int u = (t < BN && t >= off) ? lscan[t - off] : 0;
        __syncthreads();
        if (t < BN) lscan[t] += u;
        __syncthreads();
    }
    if (t < BN) {
        int excl = lscan[t] - lcnt[t];
        lcur[t] = excl;
        int node = (b << 7) + t;
        if (node < N) {
            rowptr[node] = start + excl;
            deg[node] = lcnt[t];
        }
    }
    __syncthreads();

    // Pass 2: place src ids; writes land in [start, start+cnt) contiguously.
    for (int j = t; j < cnt; j += 256) {
        unsigned r = recs[start + j];
        int pos = atomicAdd(&lcur[r >> 17], 1);
        col[start + pos] = (int)(r & 0x1FFFF);
    }
}

// ===========================================================================
// Gather (round-6 proven): one wave per node, lane owns float2 of the row.
// ===========================================================================
__global__ __launch_bounds__(256) void gather_kernel(
    const float* __restrict__ x,
    const int* __restrict__ rowptr,
    const int* __restrict__ deg,
    const int* __restrict__ col,
    float* __restrict__ agg,            // = d_out
    int N)
{
    const int n = blockIdx.x * 4 + (threadIdx.x >> 6);
    if (n >= N) return;
    const int lane = threadIdx.x & 63;

    const int start = rowptr[n];
    const int cnt = deg[n];
    const float2* x2 = (const float2*)x;

    float2 acc = make_float2(0.0f, 0.0f);
    for (int j0 = 0; j0 < cnt; j0 += 64) {
        int idx = 0;
        if (j0 + lane < cnt) idx = col[start + j0 + lane];
        const int m = min(64, cnt - j0);
        int jj = 0;
        for (; jj + 4 <= m; jj += 4) {
            int n0 = __shfl(idx, jj);
            int n1 = __shfl(idx, jj + 1);
            int n2 = __shfl(idx, jj + 2);
            int n3 = __shfl(idx, jj + 3);
            float2 v0 = x2[(size_t)n0 * 64 + lane];
            float2 v1 = x2[(size_t)n1 * 64 + lane];
            float2 v2 = x2[(size_t)n2 * 64 + lane];
            float2 v3 = x2[(size_t)n3 * 64 + lane];
            acc.x += v0.x + v1.x + v2.x + v3.x;
            acc.y += v0.y + v1.y + v2.y + v3.y;
        }
        for (; jj < m; ++jj) {
            int nb = __shfl(idx, jj);
            float2 v = x2[(size_t)nb * 64 + lane];
            acc.x += v.x; acc.y += v.y;
        }
    }
    const float inv = 1.0f / fmaxf((float)cnt, 1.0f);
    acc.x *= inv; acc.y *= inv;
    ((float2*)agg)[(size_t)n * 64 + lane] = acc;
}

// ===========================================================================
// W pre-convert + MFMA GEMM (round-5/6 proven, unchanged).
// ===========================================================================
__global__ __launch_bounds__(256) void wconv_kernel(
    const float* __restrict__ Ws, const float* __restrict__ Wn,
    unsigned short* __restrict__ Wb)
{
    int i = blockIdx.x * 256 + threadIdx.x;
    int n = i >> 8, k = i & 255;
    float v = (k < DIM) ? Ws[n * DIM + k] : Wn[n * DIM + (k - DIM)];
    Wb[i] = (unsigned short)f2bf(v);
}

__global__ __launch_bounds__(256) void mfma_gemm_kernel(
    const float* __restrict__ x,
    const float* __restrict__ agg,            // = d_out
    const unsigned short* __restrict__ Wb,    // [128][256] bf16
    const float* __restrict__ bias,
    float* __restrict__ out,
    int M)
{
    const int wave = threadIdx.x >> 6;
    const int lane = threadIdx.x & 63;
    const int row0 = blockIdx.x * 64 + wave * 16;
    if (row0 >= M) return;
    const int m = lane & 15;
    const int quad = lane >> 4;

    f32x4 acc[8];
    #pragma unroll
    for (int nt = 0; nt < 8; ++nt) acc[nt] = (f32x4){0.f, 0.f, 0.f, 0.f};

    const float* arow_x = x   + (size_t)(row0 + m) * DIM + quad * 8;
    const float* arow_g = agg + (size_t)(row0 + m) * DIM + quad * 8;
    const unsigned short* brow = Wb + (size_t)m * 256 + quad * 8;

    #pragma unroll
    for (int ks = 0; ks < 8; ++ks) {
        const float* ap = (ks < 4) ? (arow_x + ks * 32) : (arow_g + (ks - 4) * 32);
        float4 lo = *(const float4*)(ap);
        float4 hi = *(const float4*)(ap + 4);
        bf16x8 af;
        af[0] = f2bf(lo.x); af[1] = f2bf(lo.y); af[2] = f2bf(lo.z); af[3] = f2bf(lo.w);
        af[4] = f2bf(hi.x); af[5] = f2bf(hi.y); af[6] = f2bf(hi.z); af[7] = f2bf(hi.w);
        #pragma unroll
        for (int nt = 0; nt < 8; ++nt) {
            bf16x8 bf = *(const bf16x8*)(brow + (size_t)nt * 16 * 256 + ks * 32);
            acc[nt] = __builtin_amdgcn_mfma_f32_16x16x32_bf16(af, bf, acc[nt], 0, 0, 0);
        }
    }

    #pragma unroll
    for (int nt = 0; nt < 8; ++nt) {
        int c = nt * 16 + m;
        float b = bias[c];
        #pragma unroll
        for (int r = 0; r < 4; ++r) {
            int row = row0 + quad * 4 + r;
            out[(size_t)row * DIM + c] = fmaxf(acc[nt][r] + b, 0.0f);
        }
    }
}

// ===========================================================================
// Fallback CSR construction (round-6 proven) if ws too small / N too big.
// ===========================================================================
__global__ __launch_bounds__(256) void count_kernel(
    const int* __restrict__ ei, int* __restrict__ deg, int E)
{
    int e = blockIdx.x * blockDim.x + threadIdx.x;
    if (e >= E) return;
    atomicAdd(deg + ei[e], 1);
    atomicAdd(deg + ei[E + e], 1);
}

__global__ __launch_bounds__(1024) void scan_kernel(
    const int* __restrict__ deg, int* __restrict__ rowptr,
    int* __restrict__ cursor, int N)
{
    __shared__ int sums[1024];
    const int t = threadIdx.x;
    const int chunk = (N + 1023) >> 10;
    const int lo = t * chunk;
    const int hi = min(lo + chunk, N);
    int s = 0;
    for (int i = lo; i < hi; ++i) s += deg[i];
    sums[t] = s;
    __syncthreads();
    for (int off = 1; off < 1024; off <<= 1) {
        int v = (t >= off) ? sums[t - off] : 0;
        __syncthreads();
        sums[t] += v;
        __syncthreads();
    }
    int run = (t == 0) ? 0 : sums[t - 1];
    for (int i = lo; i < hi; ++i) {
        rowptr[i] = run;
        cursor[i] = run;
        run += deg[i];
    }
    if (t == 1023) rowptr[N] = sums[1023];
}

__global__ __launch_bounds__(256) void fill_kernel(
    const int* __restrict__ ei, int* __restrict__ cursor,
    int* __restrict__ col, int E)
{
    int e = blockIdx.x * blockDim.x + threadIdx.x;
    if (e >= E) return;
    int s = ei[e];
    int d = ei[E + e];
    int p0 = atomicAdd(cursor + d, 1);  col[p0] = s;
    int p1 = atomicAdd(cursor + s, 1);  col[p1] = d;
}

extern "C" void kernel_launch(void* const* d_in, const int* in_sizes, int n_in,
                              void* d_out, int out_size, void* d_ws, size_t ws_size,
                              hipStream_t stream) {
    const float* x    = (const float*)d_in[0];
    const int* ei     = (const int*)d_in[1];   // int32 on device (harness converts)
    const float* Ws   = (const float*)d_in[3];
    const float* Wn   = (const float*)d_in[4];
    const float* bias = (const float*)d_in[5];
    float* out        = (float*)d_out;

    const int N = in_sizes[0] / DIM;      // 100000
    const int E = in_sizes[1] / 2;        // 800000
    float* agg = out;

    const int nb = (N + BN - 1) >> 7;
    const size_t wb_bytes = (size_t)DIM * 256 * sizeof(unsigned short);  // 64 KB

    // Bucket-path ws: hist|base|cursor (3*1024) + rowptr[N] + deg[N]
    //                 + recs[2E] + col[2E] + Wb
    const size_t bucket_bytes = 3 * 1024 * sizeof(int)
                              + (size_t)2 * N * sizeof(int)
                              + (size_t)4 * E * sizeof(int) + wb_bytes;

    if (nb <= 1024 && N <= (1 << 17) && ws_size >= bucket_bytes) {
        int* hist   = (int*)d_ws;
        int* base   = hist + 1024;
        int* cursor = base + 1024;
        int* rowptr = cursor + 1024;
        int* deg    = rowptr + N;
        unsigned* recs = (unsigned*)(deg + N);
        int* col    = (int*)(recs + (size_t)2 * E);
        unsigned short* Wb = (unsigned short*)(col + (size_t)2 * E);

        hipMemsetAsync(hist, 0, 1024 * sizeof(int), stream);
        hist_kernel<<<256, 256, 0, stream>>>(ei, hist, E, nb);
        bscan_kernel<<<1, 1024, 0, stream>>>(hist, base, cursor, nb);
        bin_kernel<<<256, 256, 0, stream>>>(ei, cursor, recs, E);
        localsort_kernel<<<nb, 256, 0, stream>>>(recs, base, hist, rowptr, deg, col, N);
        gather_kernel<<<(N + 3) / 4, 256, 0, stream>>>(x, rowptr, deg, col, agg, N);

        wconv_kernel<<<(DIM * 256) / 256, 256, 0, stream>>>(Ws, Wn, Wb);
        mfma_gemm_kernel<<<(N + 63) / 64, 256, 0, stream>>>(x, agg, Wb, bias, out, N);
    } else {
        // Fallback: round-6 CSR path (proven 483 us).
        int* deg    = (int*)d_ws;
        int* rowptr = deg + N;
        int* cursor = rowptr + N + 1;
        int* col    = cursor + N;
        unsigned short* Wb = (unsigned short*)(col + (size_t)2 * E);

        hipMemsetAsync(deg, 0, (size_t)N * sizeof(int), stream);
        int eb = (E + 255) / 256;
        count_kernel<<<eb, 256, 0, stream>>>(ei, deg, E);
        scan_kernel<<<1, 1024, 0, stream>>>(deg, rowptr, cursor, N);
        fill_kernel<<<eb, 256, 0, stream>>>(ei, cursor, col, E);
        gather_kernel<<<(N + 3) / 4, 256, 0, stream>>>(x, rowptr, deg, col, agg, N);
        wconv_kernel<<<(DIM * 256) / 256, 256, 0, stream>>>(Ws, Wn, Wb);
        mfma_gemm_kernel<<<(N + 63) / 64, 256, 0, stream>>>(x, agg, Wb, bias, out, N);
    }
}

// Round 9
// 284.920 us; speedup vs baseline: 6.6997x; 2.3685x over previous
//
#include <hip/hip_runtime.h>

#define DIM 128
#define BN 128              // nodes per bucket; local dst 7 bits, src 17 bits
#define BIN_BLOCKS 128

typedef __attribute__((ext_vector_type(8))) short bf16x8;
typedef __attribute__((ext_vector_type(4))) float f32x4;

__device__ inline short f2bf(float f) {
    unsigned u = __builtin_bit_cast(unsigned, f);
    return (short)((u + 0x8000u) >> 16);
}

// ===========================================================================
// Bucketed CSR construction: hist -> bscan -> bin2 (block-binned) -> localsort
// ===========================================================================

__global__ __launch_bounds__(256) void hist_kernel(
    const int* __restrict__ ei, int* __restrict__ hist, int E, int nb)
{
    __shared__ int h[1024];
    for (int i = threadIdx.x; i < nb; i += 256) h[i] = 0;
    __syncthreads();
    const int stride = gridDim.x * 256;
    for (int e = blockIdx.x * 256 + threadIdx.x; e < E; e += stride) {
        int s = ei[e], d = ei[E + e];
        atomicAdd(&h[d >> 7], 1);
        atomicAdd(&h[s >> 7], 1);
    }
    __syncthreads();
    for (int i = threadIdx.x; i < nb; i += 256)
        if (h[i]) atomicAdd(&hist[i], h[i]);
}

__global__ __launch_bounds__(1024) void bscan_kernel(
    const int* __restrict__ hist, int* __restrict__ base,
    int* __restrict__ cursor, int nb)
{
    __shared__ int s[1024];
    const int t = threadIdx.x;
    int v = (t < nb) ? hist[t] : 0;
    s[t] = v;
    __syncthreads();
    for (int off = 1; off < 1024; off <<= 1) {
        int u = (t >= off) ? s[t - off] : 0;
        __syncthreads();
        s[t] += u;
        __syncthreads();
    }
    if (t < nb) { base[t] = s[t] - v; cursor[t] = s[t] - v; }
}

// Block-binned scatter: per-block LDS histogram -> ONE global reservation per
// (block,bucket) -> placement through LDS cursors into private contiguous
// runs (single-writer lines; cursor contention amortized 128x per block).
__global__ __launch_bounds__(256) void bin2_kernel(
    const int* __restrict__ ei, int* __restrict__ cursor,
    unsigned* __restrict__ recs, int E, int nb)
{
    __shared__ int lh[1024];
    __shared__ int lc[1024];
    const int t = threadIdx.x;
    const int per = (E + gridDim.x - 1) / gridDim.x;
    const int e0 = blockIdx.x * per;
    const int e1 = min(e0 + per, E);

    for (int i = t; i < nb; i += 256) lh[i] = 0;
    __syncthreads();
    for (int e = e0 + t; e < e1; e += 256) {
        int s = ei[e], d = ei[E + e];
        atomicAdd(&lh[d >> 7], 1);
        atomicAdd(&lh[s >> 7], 1);
    }
    __syncthreads();
    for (int i = t; i < nb; i += 256) {
        int c = lh[i];
        lc[i] = c ? atomicAdd(&cursor[i], c) : 0;
    }
    __syncthreads();
    for (int e = e0 + t; e < e1; e += 256) {   // chunk is L2-hot on re-read
        int s = ei[e], d = ei[E + e];
        int p0 = atomicAdd(&lc[d >> 7], 1);
        recs[p0] = ((unsigned)(d & 127) << 17) | (unsigned)s;
        int p1 = atomicAdd(&lc[s >> 7], 1);
        recs[p1] = ((unsigned)(s & 127) << 17) | (unsigned)d;
    }
}

// One block per bucket: node-level counting sort in LDS; emits rowptr/deg/col.
__global__ __launch_bounds__(256) void localsort_kernel(
    const unsigned* __restrict__ recs,
    const int* __restrict__ base, const int* __restrict__ hist,
    int* __restrict__ rowptr, int* __restrict__ deg,
    int* __restrict__ col, int N)
{
    __shared__ int lcnt[BN];
    __shared__ int lscan[BN];
    __shared__ int lcur[BN];

    const int b = blockIdx.x;
    const int t = threadIdx.x;
    const int start = base[b];
    const int cnt = hist[b];

    if (t < BN) lcnt[t] = 0;
    __syncthreads();
    for (int j = t; j < cnt; j += 256)
        atomicAdd(&lcnt[recs[start + j] >> 17], 1);
    __syncthreads();

    if (t < BN) lscan[t] = lcnt[t];
    __syncthreads();
    for (int off = 1; off < BN; off <<= 1) {
        int u = (t < BN && t >= off) ? lscan[t - off] : 0;
        __syncthreads();
        if (t < BN) lscan[t] += u;
        __syncthreads();
    }
    if (t < BN) {
        int excl = lscan[t] - lcnt[t];
        lcur[t] = excl;
        int node = (b << 7) + t;
        if (node < N) {
            rowptr[node] = start + excl;
            deg[node] = lcnt[t];
        }
    }
    __syncthreads();

    for (int j = t; j < cnt; j += 256) {
        unsigned r = recs[start + j];
        int pos = atomicAdd(&lcur[r >> 17], 1);
        col[start + pos] = (int)(r & 0x1FFFF);
    }
}

// ===========================================================================
// x -> bf16 pre-convert, and bf16 gather (halves L3 gather traffic).
// ===========================================================================
__global__ __launch_bounds__(256) void xconv_kernel(
    const float* __restrict__ x, unsigned short* __restrict__ xb, int total4)
{
    int i = blockIdx.x * 256 + threadIdx.x;
    if (i >= total4) return;
    float4 v = ((const float4*)x)[i];
    ushort4 o;
    o.x = (unsigned short)f2bf(v.x); o.y = (unsigned short)f2bf(v.y);
    o.z = (unsigned short)f2bf(v.z); o.w = (unsigned short)f2bf(v.w);
    ((ushort4*)xb)[i] = o;
}

// One wave per node: lane owns features [2L, 2L+1] as packed bf16 pair (4 B).
__global__ __launch_bounds__(256) void gather_bf16_kernel(
    const unsigned short* __restrict__ xb,
    const int* __restrict__ rowptr,
    const int* __restrict__ deg,
    const int* __restrict__ col,
    float* __restrict__ agg,            // = d_out
    int N)
{
    const int n = blockIdx.x * 4 + (threadIdx.x >> 6);
    if (n >= N) return;
    const int lane = threadIdx.x & 63;

    const int start = rowptr[n];
    const int cnt = deg[n];
    const unsigned* xbu = (const unsigned*)xb;   // one uint = 2 bf16 feats

    float ax = 0.f, ay = 0.f;
    for (int j0 = 0; j0 < cnt; j0 += 64) {
        int idx = 0;
        if (j0 + lane < cnt) idx = col[start + j0 + lane];
        const int m = min(64, cnt - j0);
        int jj = 0;
        for (; jj + 4 <= m; jj += 4) {
            int n0 = __shfl(idx, jj);
            int n1 = __shfl(idx, jj + 1);
            int n2 = __shfl(idx, jj + 2);
            int n3 = __shfl(idx, jj + 3);
            unsigned u0 = xbu[(size_t)n0 * 64 + lane];
            unsigned u1 = xbu[(size_t)n1 * 64 + lane];
            unsigned u2 = xbu[(size_t)n2 * 64 + lane];
            unsigned u3 = xbu[(size_t)n3 * 64 + lane];
            ax += __builtin_bit_cast(float, u0 << 16)
                + __builtin_bit_cast(float, u1 << 16)
                + __builtin_bit_cast(float, u2 << 16)
                + __builtin_bit_cast(float, u3 << 16);
            ay += __builtin_bit_cast(float, u0 & 0xFFFF0000u)
                + __builtin_bit_cast(float, u1 & 0xFFFF0000u)
                + __builtin_bit_cast(float, u2 & 0xFFFF0000u)
                + __builtin_bit_cast(float, u3 & 0xFFFF0000u);
        }
        for (; jj < m; ++jj) {
            int nb = __shfl(idx, jj);
            unsigned u = xbu[(size_t)nb * 64 + lane];
            ax += __builtin_bit_cast(float, u << 16);
            ay += __builtin_bit_cast(float, u & 0xFFFF0000u);
        }
    }
    const float inv = 1.0f / fmaxf((float)cnt, 1.0f);
    float2 o = make_float2(ax * inv, ay * inv);
    ((float2*)agg)[(size_t)n * 64 + lane] = o;
}

// fp32 gather (round-6 proven) for Path B.
__global__ __launch_bounds__(256) void gather_kernel(
    const float* __restrict__ x,
    const int* __restrict__ rowptr,
    const int* __restrict__ deg,
    const int* __restrict__ col,
    float* __restrict__ agg, int N)
{
    const int n = blockIdx.x * 4 + (threadIdx.x >> 6);
    if (n >= N) return;
    const int lane = threadIdx.x & 63;
    const int start = rowptr[n];
    const int cnt = deg[n];
    const float2* x2 = (const float2*)x;
    float2 acc = make_float2(0.0f, 0.0f);
    for (int j0 = 0; j0 < cnt; j0 += 64) {
        int idx = 0;
        if (j0 + lane < cnt) idx = col[start + j0 + lane];
        const int m = min(64, cnt - j0);
        int jj = 0;
        for (; jj + 4 <= m; jj += 4) {
            int n0 = __shfl(idx, jj);
            int n1 = __shfl(idx, jj + 1);
            int n2 = __shfl(idx, jj + 2);
            int n3 = __shfl(idx, jj + 3);
            float2 v0 = x2[(size_t)n0 * 64 + lane];
            float2 v1 = x2[(size_t)n1 * 64 + lane];
            float2 v2 = x2[(size_t)n2 * 64 + lane];
            float2 v3 = x2[(size_t)n3 * 64 + lane];
            acc.x += v0.x + v1.x + v2.x + v3.x;
            acc.y += v0.y + v1.y + v2.y + v3.y;
        }
        for (; jj < m; ++jj) {
            int nb = __shfl(idx, jj);
            float2 v = x2[(size_t)nb * 64 + lane];
            acc.x += v.x; acc.y += v.y;
        }
    }
    const float inv = 1.0f / fmaxf((float)cnt, 1.0f);
    acc.x *= inv; acc.y *= inv;
    ((float2*)agg)[(size_t)n * 64 + lane] = acc;
}

// ===========================================================================
// W pre-convert + MFMA GEMMs.
// ===========================================================================
__global__ __launch_bounds__(256) void wconv_kernel(
    const float* __restrict__ Ws, const float* __restrict__ Wn,
    unsigned short* __restrict__ Wb)
{
    int i = blockIdx.x * 256 + threadIdx.x;
    int n = i >> 8, k = i & 255;
    float v = (k < DIM) ? Ws[n * DIM + k] : Wn[n * DIM + (k - DIM)];
    Wb[i] = (unsigned short)f2bf(v);
}

// Path A: A-fragments for x-half load pre-converted bf16 directly.
__global__ __launch_bounds__(256) void mfma_gemm_xb_kernel(
    const unsigned short* __restrict__ xb,    // [M][128] bf16
    const float* __restrict__ agg,            // = d_out
    const unsigned short* __restrict__ Wb,    // [128][256] bf16
    const float* __restrict__ bias,
    float* __restrict__ out,
    int M)
{
    const int wave = threadIdx.x >> 6;
    const int lane = threadIdx.x & 63;
    const int row0 = blockIdx.x * 64 + wave * 16;
    if (row0 >= M) return;
    const int m = lane & 15;
    const int quad = lane >> 4;

    f32x4 acc[8];
    #pragma unroll
    for (int nt = 0; nt < 8; ++nt) acc[nt] = (f32x4){0.f, 0.f, 0.f, 0.f};

    const unsigned short* arow_x = xb + (size_t)(row0 + m) * DIM + quad * 8;
    const float* arow_g = agg + (size_t)(row0 + m) * DIM + quad * 8;
    const unsigned short* brow = Wb + (size_t)m * 256 + quad * 8;

    #pragma unroll
    for (int ks = 0; ks < 8; ++ks) {
        bf16x8 af;
        if (ks < 4) {
            af = *(const bf16x8*)(arow_x + ks * 32);
        } else {
            const float* ap = arow_g + (ks - 4) * 32;
            float4 lo = *(const float4*)(ap);
            float4 hi = *(const float4*)(ap + 4);
            af[0] = f2bf(lo.x); af[1] = f2bf(lo.y); af[2] = f2bf(lo.z); af[3] = f2bf(lo.w);
            af[4] = f2bf(hi.x); af[5] = f2bf(hi.y); af[6] = f2bf(hi.z); af[7] = f2bf(hi.w);
        }
        #pragma unroll
        for (int nt = 0; nt < 8; ++nt) {
            bf16x8 bf = *(const bf16x8*)(brow + (size_t)nt * 16 * 256 + ks * 32);
            acc[nt] = __builtin_amdgcn_mfma_f32_16x16x32_bf16(af, bf, acc[nt], 0, 0, 0);
        }
    }

    #pragma unroll
    for (int nt = 0; nt < 8; ++nt) {
        int c = nt * 16 + m;
        float b = bias[c];
        #pragma unroll
        for (int r = 0; r < 4; ++r) {
            int row = row0 + quad * 4 + r;
            out[(size_t)row * DIM + c] = fmaxf(acc[nt][r] + b, 0.0f);
        }
    }
}

// Path B/C: fp32-x variant (round-5..8 proven).
__global__ __launch_bounds__(256) void mfma_gemm_kernel(
    const float* __restrict__ x,
    const float* __restrict__ agg,
    const unsigned short* __restrict__ Wb,
    const float* __restrict__ bias,
    float* __restrict__ out,
    int M)
{
    const int wave = threadIdx.x >> 6;
    const int lane = threadIdx.x & 63;
    const int row0 = blockIdx.x * 64 + wave * 16;
    if (row0 >= M) return;
    const int m = lane & 15;
    const int quad = lane >> 4;

    f32x4 acc[8];
    #pragma unroll
    for (int nt = 0; nt < 8; ++nt) acc[nt] = (f32x4){0.f, 0.f, 0.f, 0.f};

    const float* arow_x = x   + (size_t)(row0 + m) * DIM + quad * 8;
    const float* arow_g = agg + (size_t)(row0 + m) * DIM + quad * 8;
    const unsigned short* brow = Wb + (size_t)m * 256 + quad * 8;

    #pragma unroll
    for (int ks = 0; ks < 8; ++ks) {
        const float* ap = (ks < 4) ? (arow_x + ks * 32) : (arow_g + (ks - 4) * 32);
        float4 lo = *(const float4*)(ap);
        float4 hi = *(const float4*)(ap + 4);
        bf16x8 af;
        af[0] = f2bf(lo.x); af[1] = f2bf(lo.y); af[2] = f2bf(lo.z); af[3] = f2bf(lo.w);
        af[4] = f2bf(hi.x); af[5] = f2bf(hi.y); af[6] = f2bf(hi.z); af[7] = f2bf(hi.w);
        #pragma unroll
        for (int nt = 0; nt < 8; ++nt) {
            bf16x8 bf = *(const bf16x8*)(brow + (size_t)nt * 16 * 256 + ks * 32);
            acc[nt] = __builtin_amdgcn_mfma_f32_16x16x32_bf16(af, bf, acc[nt], 0, 0, 0);
        }
    }

    #pragma unroll
    for (int nt = 0; nt < 8; ++nt) {
        int c = nt * 16 + m;
        float b = bias[c];
        #pragma unroll
        for (int r = 0; r < 4; ++r) {
            int row = row0 + quad * 4 + r;
            out[(size_t)row * DIM + c] = fmaxf(acc[nt][r] + b, 0.0f);
        }
    }
}

// ===========================================================================
// Path C fallback: round-6 CSR construction.
// ===========================================================================
__global__ __launch_bounds__(256) void count_kernel(
    const int* __restrict__ ei, int* __restrict__ deg, int E)
{
    int e = blockIdx.x * blockDim.x + threadIdx.x;
    if (e >= E) return;
    atomicAdd(deg + ei[e], 1);
    atomicAdd(deg + ei[E + e], 1);
}

__global__ __launch_bounds__(1024) void scan_kernel(
    const int* __restrict__ deg, int* __restrict__ rowptr,
    int* __restrict__ cursor, int N)
{
    __shared__ int sums[1024];
    const int t = threadIdx.x;
    const int chunk = (N + 1023) >> 10;
    const int lo = t * chunk;
    const int hi = min(lo + chunk, N);
    int s = 0;
    for (int i = lo; i < hi; ++i) s += deg[i];
    sums[t] = s;
    __syncthreads();
    for (int off = 1; off < 1024; off <<= 1) {
        int v = (t >= off) ? sums[t - off] : 0;
        __syncthreads();
        sums[t] += v;
        __syncthreads();
    }
    int run = (t == 0) ? 0 : sums[t - 1];
    for (int i = lo; i < hi; ++i) {
        rowptr[i] = run;
        cursor[i] = run;
        run += deg[i];
    }
    if (t == 1023) rowptr[N] = sums[1023];
}

__global__ __launch_bounds__(256) void fill_kernel(
    const int* __restrict__ ei, int* __restrict__ cursor,
    int* __restrict__ col, int E)
{
    int e = blockIdx.x * blockDim.x + threadIdx.x;
    if (e >= E) return;
    int s = ei[e];
    int d = ei[E + e];
    int p0 = atomicAdd(cursor + d, 1);  col[p0] = s;
    int p1 = atomicAdd(cursor + s, 1);  col[p1] = d;
}

extern "C" void kernel_launch(void* const* d_in, const int* in_sizes, int n_in,
                              void* d_out, int out_size, void* d_ws, size_t ws_size,
                              hipStream_t stream) {
    const float* x    = (const float*)d_in[0];
    const int* ei     = (const int*)d_in[1];
    const float* Ws   = (const float*)d_in[3];
    const float* Wn   = (const float*)d_in[4];
    const float* bias = (const float*)d_in[5];
    float* out        = (float*)d_out;

    const int N = in_sizes[0] / DIM;      // 100000
    const int E = in_sizes[1] / 2;        // 800000
    float* agg = out;

    const int nb = (N + BN - 1) >> 7;
    const size_t wb_bytes = (size_t)DIM * 256 * sizeof(unsigned short);  // 64 KB

    // ws layout (Path A): hist|base|cursor (3*1024 int) | rowptr[N] | deg[N]
    //                     | recs[2E] | col[2E] | xb[N*128 bf16] | Wb
    const size_t head_bytes = (3 * 1024 + (size_t)2 * N + (size_t)4 * E) * sizeof(int);
    const size_t xb_bytes   = (size_t)N * DIM * sizeof(unsigned short);
    const size_t pathA = head_bytes + xb_bytes + wb_bytes;
    const size_t pathB = head_bytes + wb_bytes;             // proven 13.7 MB

    if (nb <= 1024 && N <= (1 << 17) && ws_size >= pathB) {
        int* hist   = (int*)d_ws;
        int* base   = hist + 1024;
        int* cursor = base + 1024;
        int* rowptr = cursor + 1024;
        int* deg    = rowptr + N;
        unsigned* recs = (unsigned*)(deg + N);
        int* col    = (int*)(recs + (size_t)2 * E);
        unsigned short* xb = (unsigned short*)(col + (size_t)2 * E);
        const bool useXb = (ws_size >= pathA);
        unsigned short* Wb = useXb ? (xb + (size_t)N * DIM) : xb;

        hipMemsetAsync(hist, 0, 1024 * sizeof(int), stream);
        if (useXb)
            xconv_kernel<<<(N * (DIM / 4) + 255) / 256, 256, 0, stream>>>(x, xb, N * (DIM / 4));
        hist_kernel<<<256, 256, 0, stream>>>(ei, hist, E, nb);
        bscan_kernel<<<1, 1024, 0, stream>>>(hist, base, cursor, nb);
        bin2_kernel<<<BIN_BLOCKS, 256, 0, stream>>>(ei, cursor, recs, E, nb);
        localsort_kernel<<<nb, 256, 0, stream>>>(recs, base, hist, rowptr, deg, col, N);
        wconv_kernel<<<(DIM * 256) / 256, 256, 0, stream>>>(Ws, Wn, Wb);

        if (useXb) {
            gather_bf16_kernel<<<(N + 3) / 4, 256, 0, stream>>>(xb, rowptr, deg, col, agg, N);
            mfma_gemm_xb_kernel<<<(N + 63) / 64, 256, 0, stream>>>(xb, agg, Wb, bias, out, N);
        } else {
            gather_kernel<<<(N + 3) / 4, 256, 0, stream>>>(x, rowptr, deg, col, agg, N);
            mfma_gemm_kernel<<<(N + 63) / 64, 256, 0, stream>>>(x, agg, Wb, bias, out, N);
        }
    } else {
        // Path C: round-6 CSR (proven).
        int* deg    = (int*)d_ws;
        int* rowptr = deg + N;
        int* cursor = rowptr + N + 1;
        int* col    = cursor + N;
        unsigned short* Wb = (unsigned short*)(col + (size_t)2 * E);

        hipMemsetAsync(deg, 0, (size_t)N * sizeof(int), stream);
        int eb = (E + 255) / 256;
        count_kernel<<<eb, 256, 0, stream>>>(ei, deg, E);
        scan_kernel<<<1, 1024, 0, stream>>>(deg, rowptr, cursor, N);
        fill_kernel<<<eb, 256, 0, stream>>>(ei, cursor, col, E);
        gather_kernel<<<(N + 3) / 4, 256, 0, stream>>>(x, rowptr, deg, col, agg, N);
        wconv_kernel<<<(DIM * 256) / 256, 256, 0, stream>>>(Ws, Wn, Wb);
        mfma_gemm_kernel<<<(N + 63) / 64, 256, 0, stream>>>(x, agg, Wb, bias, out, N);
    }
}

// Round 10
// 275.587 us; speedup vs baseline: 6.9266x; 1.0339x over previous
//
#include <hip/hip_runtime.h>

#define DIM 128
#define BN 128              // nodes per bucket; local dst 7 bits, src 17 bits
#define BIN_BLOCKS 128

typedef __attribute__((ext_vector_type(8))) short bf16x8;
typedef __attribute__((ext_vector_type(4))) float f32x4;

__device__ inline short f2bf(float f) {
    unsigned u = __builtin_bit_cast(unsigned, f);
    return (short)((u + 0x8000u) >> 16);
}

// ===========================================================================
// Bucketed CSR construction (round-9 proven): hist -> bscan -> bin2 -> localsort
// ===========================================================================

__global__ __launch_bounds__(256) void hist_kernel(
    const int* __restrict__ ei, int* __restrict__ hist, int E, int nb)
{
    __shared__ int h[1024];
    for (int i = threadIdx.x; i < nb; i += 256) h[i] = 0;
    __syncthreads();
    const int stride = gridDim.x * 256;
    for (int e = blockIdx.x * 256 + threadIdx.x; e < E; e += stride) {
        int s = ei[e], d = ei[E + e];
        atomicAdd(&h[d >> 7], 1);
        atomicAdd(&h[s >> 7], 1);
    }
    __syncthreads();
    for (int i = threadIdx.x; i < nb; i += 256)
        if (h[i]) atomicAdd(&hist[i], h[i]);
}

__global__ __launch_bounds__(1024) void bscan_kernel(
    const int* __restrict__ hist, int* __restrict__ base,
    int* __restrict__ cursor, int nb)
{
    __shared__ int s[1024];
    const int t = threadIdx.x;
    int v = (t < nb) ? hist[t] : 0;
    s[t] = v;
    __syncthreads();
    for (int off = 1; off < 1024; off <<= 1) {
        int u = (t >= off) ? s[t - off] : 0;
        __syncthreads();
        s[t] += u;
        __syncthreads();
    }
    if (t < nb) { base[t] = s[t] - v; cursor[t] = s[t] - v; }
}

// Block-binned scatter: one global reservation per (block,bucket).
__global__ __launch_bounds__(256) void bin2_kernel(
    const int* __restrict__ ei, int* __restrict__ cursor,
    unsigned* __restrict__ recs, int E, int nb)
{
    __shared__ int lh[1024];
    __shared__ int lc[1024];
    const int t = threadIdx.x;
    const int per = (E + gridDim.x - 1) / gridDim.x;
    const int e0 = blockIdx.x * per;
    const int e1 = min(e0 + per, E);

    for (int i = t; i < nb; i += 256) lh[i] = 0;
    __syncthreads();
    for (int e = e0 + t; e < e1; e += 256) {
        int s = ei[e], d = ei[E + e];
        atomicAdd(&lh[d >> 7], 1);
        atomicAdd(&lh[s >> 7], 1);
    }
    __syncthreads();
    for (int i = t; i < nb; i += 256) {
        int c = lh[i];
        lc[i] = c ? atomicAdd(&cursor[i], c) : 0;
    }
    __syncthreads();
    for (int e = e0 + t; e < e1; e += 256) {
        int s = ei[e], d = ei[E + e];
        int p0 = atomicAdd(&lc[d >> 7], 1);
        recs[p0] = ((unsigned)(d & 127) << 17) | (unsigned)s;
        int p1 = atomicAdd(&lc[s >> 7], 1);
        recs[p1] = ((unsigned)(s & 127) << 17) | (unsigned)d;
    }
}

__global__ __launch_bounds__(256) void localsort_kernel(
    const unsigned* __restrict__ recs,
    const int* __restrict__ base, const int* __restrict__ hist,
    int* __restrict__ rowptr, int* __restrict__ deg,
    int* __restrict__ col, int N)
{
    __shared__ int lcnt[BN];
    __shared__ int lscan[BN];
    __shared__ int lcur[BN];

    const int b = blockIdx.x;
    const int t = threadIdx.x;
    const int start = base[b];
    const int cnt = hist[b];

    if (t < BN) lcnt[t] = 0;
    __syncthreads();
    for (int j = t; j < cnt; j += 256)
        atomicAdd(&lcnt[recs[start + j] >> 17], 1);
    __syncthreads();

    if (t < BN) lscan[t] = lcnt[t];
    __syncthreads();
    for (int off = 1; off < BN; off <<= 1) {
        int u = (t < BN && t >= off) ? lscan[t - off] : 0;
        __syncthreads();
        if (t < BN) lscan[t] += u;
        __syncthreads();
    }
    if (t < BN) {
        int excl = lscan[t] - lcnt[t];
        lcur[t] = excl;
        int node = (b << 7) + t;
        if (node < N) {
            rowptr[node] = start + excl;
            deg[node] = lcnt[t];
        }
    }
    __syncthreads();

    for (int j = t; j < cnt; j += 256) {
        unsigned r = recs[start + j];
        int pos = atomicAdd(&lcur[r >> 17], 1);
        col[start + pos] = (int)(r & 0x1FFFF);
    }
}

// ===========================================================================
// x -> bf16 pre-convert.
// ===========================================================================
__global__ __launch_bounds__(256) void xconv_kernel(
    const float* __restrict__ x, unsigned short* __restrict__ xb, int total4)
{
    int i = blockIdx.x * 256 + threadIdx.x;
    if (i >= total4) return;
    float4 v = ((const float4*)x)[i];
    ushort4 o;
    o.x = (unsigned short)f2bf(v.x); o.y = (unsigned short)f2bf(v.y);
    o.z = (unsigned short)f2bf(v.z); o.w = (unsigned short)f2bf(v.w);
    ((ushort4*)xb)[i] = o;
}

// ===========================================================================
// Gather, bf16 in -> bf16 out (aggb in ws). One wave/node, ILP 8.
// ===========================================================================
__global__ __launch_bounds__(256) void gather_bb_kernel(
    const unsigned short* __restrict__ xb,
    const int* __restrict__ rowptr,
    const int* __restrict__ deg,
    const int* __restrict__ col,
    unsigned short* __restrict__ aggb,   // [N][128] bf16
    int N)
{
    const int n = blockIdx.x * 4 + (threadIdx.x >> 6);
    if (n >= N) return;
    const int lane = threadIdx.x & 63;

    const int start = rowptr[n];
    const int cnt = deg[n];
    const unsigned* xbu = (const unsigned*)xb;   // one uint = 2 bf16 feats

    float ax = 0.f, ay = 0.f;
    for (int j0 = 0; j0 < cnt; j0 += 64) {
        int idx = 0;
        if (j0 + lane < cnt) idx = col[start + j0 + lane];
        const int m = min(64, cnt - j0);
        int jj = 0;
        for (; jj + 8 <= m; jj += 8) {
            unsigned u[8];
            #pragma unroll
            for (int q = 0; q < 8; ++q) {
                int nn = __shfl(idx, jj + q);
                u[q] = xbu[(size_t)nn * 64 + lane];
            }
            #pragma unroll
            for (int q = 0; q < 8; ++q) {
                ax += __builtin_bit_cast(float, u[q] << 16);
                ay += __builtin_bit_cast(float, u[q] & 0xFFFF0000u);
            }
        }
        for (; jj < m; ++jj) {
            int nn = __shfl(idx, jj);
            unsigned u = xbu[(size_t)nn * 64 + lane];
            ax += __builtin_bit_cast(float, u << 16);
            ay += __builtin_bit_cast(float, u & 0xFFFF0000u);
        }
    }
    const float inv = 1.0f / fmaxf((float)cnt, 1.0f);
    unsigned lo = (unsigned)(unsigned short)f2bf(ax * inv);
    unsigned hi = (unsigned)(unsigned short)f2bf(ay * inv);
    ((unsigned*)aggb)[(size_t)n * 64 + lane] = lo | (hi << 16);
}

// Round-9 fallback gather: bf16 in -> fp32 agg in d_out.
__global__ __launch_bounds__(256) void gather_bf16_kernel(
    const unsigned short* __restrict__ xb,
    const int* __restrict__ rowptr,
    const int* __restrict__ deg,
    const int* __restrict__ col,
    float* __restrict__ agg, int N)
{
    const int n = blockIdx.x * 4 + (threadIdx.x >> 6);
    if (n >= N) return;
    const int lane = threadIdx.x & 63;
    const int start = rowptr[n];
    const int cnt = deg[n];
    const unsigned* xbu = (const unsigned*)xb;
    float ax = 0.f, ay = 0.f;
    for (int j0 = 0; j0 < cnt; j0 += 64) {
        int idx = 0;
        if (j0 + lane < cnt) idx = col[start + j0 + lane];
        const int m = min(64, cnt - j0);
        for (int jj = 0; jj < m; ++jj) {
            int nn = __shfl(idx, jj);
            unsigned u = xbu[(size_t)nn * 64 + lane];
            ax += __builtin_bit_cast(float, u << 16);
            ay += __builtin_bit_cast(float, u & 0xFFFF0000u);
        }
    }
    const float inv = 1.0f / fmaxf((float)cnt, 1.0f);
    ((float2*)agg)[(size_t)n * 64 + lane] = make_float2(ax * inv, ay * inv);
}

// ===========================================================================
// W pre-convert + MFMA GEMMs.
// ===========================================================================
__global__ __launch_bounds__(256) void wconv_kernel(
    const float* __restrict__ Ws, const float* __restrict__ Wn,
    unsigned short* __restrict__ Wb)
{
    int i = blockIdx.x * 256 + threadIdx.x;
    int n = i >> 8, k = i & 255;
    float v = (k < DIM) ? Ws[n * DIM + k] : Wn[n * DIM + (k - DIM)];
    Wb[i] = (unsigned short)f2bf(v);
}

// New GEMM: all-bf16 A (xb | aggb), 32 rows/wave (2 m-tiles reuse each B frag).
__global__ __launch_bounds__(256) void mfma_gemm_bb_kernel(
    const unsigned short* __restrict__ xb,     // [M][128] bf16
    const unsigned short* __restrict__ aggb,   // [M][128] bf16
    const unsigned short* __restrict__ Wb,     // [128][256] bf16
    const float* __restrict__ bias,
    float* __restrict__ out,
    int M)
{
    const int wave = threadIdx.x >> 6;
    const int lane = threadIdx.x & 63;
    const int row0 = blockIdx.x * 128 + wave * 32;
    if (row0 >= M) return;
    const int m = lane & 15;
    const int quad = lane >> 4;

    // clamp row indices for tail safety (stores are guarded)
    const int rA = min(row0 + m, M - 1);
    const int rB = min(row0 + 16 + m, M - 1);

    f32x4 acc[2][8];
    #pragma unroll
    for (int g = 0; g < 2; ++g)
        #pragma unroll
        for (int nt = 0; nt < 8; ++nt) acc[g][nt] = (f32x4){0.f, 0.f, 0.f, 0.f};

    const unsigned short* ax0 = xb   + (size_t)rA * DIM + quad * 8;
    const unsigned short* ax1 = xb   + (size_t)rB * DIM + quad * 8;
    const unsigned short* ag0 = aggb + (size_t)rA * DIM + quad * 8;
    const unsigned short* ag1 = aggb + (size_t)rB * DIM + quad * 8;
    const unsigned short* brow = Wb + (size_t)m * 256 + quad * 8;

    #pragma unroll
    for (int ks = 0; ks < 8; ++ks) {
        bf16x8 af0, af1;
        if (ks < 4) {
            af0 = *(const bf16x8*)(ax0 + ks * 32);
            af1 = *(const bf16x8*)(ax1 + ks * 32);
        } else {
            af0 = *(const bf16x8*)(ag0 + (ks - 4) * 32);
            af1 = *(const bf16x8*)(ag1 + (ks - 4) * 32);
        }
        #pragma unroll
        for (int nt = 0; nt < 8; ++nt) {
            bf16x8 bf = *(const bf16x8*)(brow + (size_t)nt * 16 * 256 + ks * 32);
            acc[0][nt] = __builtin_amdgcn_mfma_f32_16x16x32_bf16(af0, bf, acc[0][nt], 0, 0, 0);
            acc[1][nt] = __builtin_amdgcn_mfma_f32_16x16x32_bf16(af1, bf, acc[1][nt], 0, 0, 0);
        }
    }

    #pragma unroll
    for (int g = 0; g < 2; ++g) {
        #pragma unroll
        for (int nt = 0; nt < 8; ++nt) {
            int c = nt * 16 + m;
            float b = bias[c];
            #pragma unroll
            for (int r = 0; r < 4; ++r) {
                int row = row0 + g * 16 + quad * 4 + r;
                if (row < M)
                    out[(size_t)row * DIM + c] = fmaxf(acc[g][nt][r] + b, 0.0f);
            }
        }
    }
}

// Round-9 fallback GEMM: xb bf16 + agg fp32 (from d_out).
__global__ __launch_bounds__(256) void mfma_gemm_xb_kernel(
    const unsigned short* __restrict__ xb,
    const float* __restrict__ agg,
    const unsigned short* __restrict__ Wb,
    const float* __restrict__ bias,
    float* __restrict__ out,
    int M)
{
    const int wave = threadIdx.x >> 6;
    const int lane = threadIdx.x & 63;
    const int row0 = blockIdx.x * 64 + wave * 16;
    if (row0 >= M) return;
    const int m = lane & 15;
    const int quad = lane >> 4;

    f32x4 acc[8];
    #pragma unroll
    for (int nt = 0; nt < 8; ++nt) acc[nt] = (f32x4){0.f, 0.f, 0.f, 0.f};

    const unsigned short* arow_x = xb + (size_t)(row0 + m) * DIM + quad * 8;
    const float* arow_g = agg + (size_t)(row0 + m) * DIM + quad * 8;
    const unsigned short* brow = Wb + (size_t)m * 256 + quad * 8;

    #pragma unroll
    for (int ks = 0; ks < 8; ++ks) {
        bf16x8 af;
        if (ks < 4) {
            af = *(const bf16x8*)(arow_x + ks * 32);
        } else {
            const float* ap = arow_g + (ks - 4) * 32;
            float4 lo = *(const float4*)(ap);
            float4 hi = *(const float4*)(ap + 4);
            af[0] = f2bf(lo.x); af[1] = f2bf(lo.y); af[2] = f2bf(lo.z); af[3] = f2bf(lo.w);
            af[4] = f2bf(hi.x); af[5] = f2bf(hi.y); af[6] = f2bf(hi.z); af[7] = f2bf(hi.w);
        }
        #pragma unroll
        for (int nt = 0; nt < 8; ++nt) {
            bf16x8 bf = *(const bf16x8*)(brow + (size_t)nt * 16 * 256 + ks * 32);
            acc[nt] = __builtin_amdgcn_mfma_f32_16x16x32_bf16(af, bf, acc[nt], 0, 0, 0);
        }
    }

    #pragma unroll
    for (int nt = 0; nt < 8; ++nt) {
        int c = nt * 16 + m;
        float b = bias[c];
        #pragma unroll
        for (int r = 0; r < 4; ++r) {
            int row = row0 + quad * 4 + r;
            out[(size_t)row * DIM + c] = fmaxf(acc[nt][r] + b, 0.0f);
        }
    }
}

extern "C" void kernel_launch(void* const* d_in, const int* in_sizes, int n_in,
                              void* d_out, int out_size, void* d_ws, size_t ws_size,
                              hipStream_t stream) {
    const float* x    = (const float*)d_in[0];
    const int* ei     = (const int*)d_in[1];
    const float* Ws   = (const float*)d_in[3];
    const float* Wn   = (const float*)d_in[4];
    const float* bias = (const float*)d_in[5];
    float* out        = (float*)d_out;

    const int N = in_sizes[0] / DIM;      // 100000
    const int E = in_sizes[1] / 2;        // 800000

    const int nb = (N + BN - 1) >> 7;
    const size_t wb_bytes = (size_t)DIM * 256 * sizeof(unsigned short);  // 64 KB

    // ws layout: hist|base|cursor (3*1024 int) | rowptr[N] | deg[N]
    //            | recs[2E] | col[2E] | xb[N*128 u16] | (aggb[N*128 u16]) | Wb
    const size_t head_bytes = (3 * 1024 + (size_t)2 * N + (size_t)4 * E) * sizeof(int);
    const size_t xb_bytes   = (size_t)N * DIM * sizeof(unsigned short);
    const size_t pathA2 = head_bytes + 2 * xb_bytes + wb_bytes;  // ~65 MB
    const size_t pathA  = head_bytes + xb_bytes + wb_bytes;      // proven round 9

    int* hist   = (int*)d_ws;
    int* base   = hist + 1024;
    int* cursor = base + 1024;
    int* rowptr = cursor + 1024;
    int* deg    = rowptr + N;
    unsigned* recs = (unsigned*)(deg + N);
    int* col    = (int*)(recs + (size_t)2 * E);
    unsigned short* xb = (unsigned short*)(col + (size_t)2 * E);

    hipMemsetAsync(hist, 0, 1024 * sizeof(int), stream);
    xconv_kernel<<<(N * (DIM / 4) + 255) / 256, 256, 0, stream>>>(x, xb, N * (DIM / 4));
    hist_kernel<<<256, 256, 0, stream>>>(ei, hist, E, nb);
    bscan_kernel<<<1, 1024, 0, stream>>>(hist, base, cursor, nb);
    bin2_kernel<<<BIN_BLOCKS, 256, 0, stream>>>(ei, cursor, recs, E, nb);
    localsort_kernel<<<nb, 256, 0, stream>>>(recs, base, hist, rowptr, deg, col, N);

    if (ws_size >= pathA2) {
        unsigned short* aggb = xb + (size_t)N * DIM;
        unsigned short* Wb   = aggb + (size_t)N * DIM;
        wconv_kernel<<<(DIM * 256) / 256, 256, 0, stream>>>(Ws, Wn, Wb);
        gather_bb_kernel<<<(N + 3) / 4, 256, 0, stream>>>(xb, rowptr, deg, col, aggb, N);
        mfma_gemm_bb_kernel<<<(N + 127) / 128, 256, 0, stream>>>(xb, aggb, Wb, bias, out, N);
    } else {
        // Round-9 proven path (ws >= pathA confirmed by profile).
        float* agg = out;
        unsigned short* Wb = xb + (size_t)N * DIM;
        wconv_kernel<<<(DIM * 256) / 256, 256, 0, stream>>>(Ws, Wn, Wb);
        gather_bf16_kernel<<<(N + 3) / 4, 256, 0, stream>>>(xb, rowptr, deg, col, agg, N);
        mfma_gemm_xb_kernel<<<(N + 63) / 64, 256, 0, stream>>>(xb, agg, Wb, bias, out, N);
    }
}